// Round 3
// baseline (1315.948 us; speedup 1.0000x reference)
//
#include <hip/hip_runtime.h>

#define NB 2048
#define NT 1024

// sigmoid via native exp2 + rcp (v_exp_f32, v_rcp_f32)
__device__ __forceinline__ float sig_fast(float x) {
    return __builtin_amdgcn_rcpf(1.0f + exp2f(-1.4426950408889634f * x));
}
// tanh(x) = 2*sigmoid(2x) - 1
__device__ __forceinline__ float tanh_fast(float x) {
    return fmaf(2.0f, __builtin_amdgcn_rcpf(1.0f + exp2f(-2.8853900817779268f * x)), -1.0f);
}

__global__ void zero_loss_kernel(float* out) { out[0] = 0.0f; }

// Plain struct of scalars (not ext_vector) so each member is a real lvalue
// for the inline-asm register pin, and SROA splits it into 4 independent VGPRs.
struct F4 { float x, y, z, w; };

#define LD4(P, i) (*(const float4*)&(P)[i])
#define LOADQ(dst, p, i) { float4 r_ = LD4(p, i); dst.x=r_.x; dst.y=r_.y; dst.z=r_.z; dst.w=r_.w; }
// Pin: inline asm is not rematerializable -> the loads above cannot be sunk
// back into the T-loop by the scheduler. With waves_per_eu(2,2) there is no
// pressure incentive to spill either.
#define PIN(v) asm("" : "+v"((v).x), "+v"((v).y), "+v"((v).z), "+v"((v).w))

#define DECL_ROW(n, src, row)                                 \
  F4 n##0, n##1, n##2, n##3, n##4, n##5, n##6, n##7;          \
  LOADQ(n##0, src, (row)*32 +  0)                             \
  LOADQ(n##1, src, (row)*32 +  4)                             \
  LOADQ(n##2, src, (row)*32 +  8)                             \
  LOADQ(n##3, src, (row)*32 + 12)                             \
  LOADQ(n##4, src, (row)*32 + 16)                             \
  LOADQ(n##5, src, (row)*32 + 20)                             \
  LOADQ(n##6, src, (row)*32 + 24)                             \
  LOADQ(n##7, src, (row)*32 + 28)                             \
  PIN(n##0); PIN(n##1); PIN(n##2); PIN(n##3);                 \
  PIN(n##4); PIN(n##5); PIN(n##6); PIN(n##7);

#define MAC4(aa, ab, wA, wB, h)                                \
  aa = fmaf((wA).x, (h).x, aa); ab = fmaf((wB).x, (h).x, ab);  \
  aa = fmaf((wA).y, (h).y, aa); ab = fmaf((wB).y, (h).y, ab);  \
  aa = fmaf((wA).z, (h).z, aa); ab = fmaf((wB).z, (h).z, ab);  \
  aa = fmaf((wA).w, (h).w, aa); ab = fmaf((wB).w, (h).w, ab);

// Grid = 2048 waves over 1024 SIMDs -> at most 2 waves/SIMD. Tell the backend
// that IS the target (min=max=2) so it allocates up to 256 VGPRs instead of
// rematerializing weight loads to chase 4-wave occupancy the grid can't use.
__global__ __launch_bounds__(64) __attribute__((amdgpu_waves_per_eu(2, 2)))
void decoder_lstm_kernel(const float* __restrict__ seq,    // (B,T,1)
                         const float* __restrict__ z,      // (B,32)
                         const float* __restrict__ w_ih0,  // (128,1)
                         const float* __restrict__ w_hh0,  // (128,32)
                         const float* __restrict__ b_ih0,  // (128,)
                         const float* __restrict__ b_hh0,  // (128,)
                         const float* __restrict__ w_ih1,  // (128,32)
                         const float* __restrict__ w_hh1,  // (128,32)
                         const float* __restrict__ b_ih1,  // (128,)
                         const float* __restrict__ b_hh1,  // (128,)
                         const float* __restrict__ w_out,  // (1,32)
                         const float* __restrict__ b_out,  // (1,)
                         float* __restrict__ out)          // [0]=loss, [1..]=recovered (B,T,1)
{
    const int b  = blockIdx.x;     // one wave per batch element
    const int l  = threadIdx.x;    // 0..63
    const int lo = l & 31;

    // 64-float rows: slots 32..63 are padding so ALL lanes store unconditionally
    __shared__ float4 sh0[16];
    __shared__ float4 sh1[16];

    // lane<32 : rA=i-row, rB=g-row ; lane>=32: rA=f-row, rB=o-row
    const int rA = l;
    const int rB = l + 64;

    const float wih0A  = w_ih0[rA];
    const float wih0B  = w_ih0[rB];
    const float bias0A = b_ih0[rA] + b_hh0[rA];
    const float bias0B = b_ih0[rB] + b_hh0[rB];
    const float bias1A = b_ih1[rA] + b_hh1[rA];
    const float bias1B = b_ih1[rB] + b_hh1[rB];

    // 48 pinned F4 = 192 VGPRs of weights. Registers are the only storage
    // tier with enough BW (LDS pipe would be ~3x oversubscribed).
    DECL_ROW(w0A, w_hh0, rA)
    DECL_ROW(w0B, w_hh0, rB)
    DECL_ROW(wiA, w_ih1, rA)
    DECL_ROW(wiB, w_ih1, rB)
    DECL_ROW(whA, w_hh1, rA)
    DECL_ROW(whB, w_hh1, rB)

    // Branchless activation constants:
    //   gate B on lane<32 is g (tanh): exp arg scale -2*log2e, v = 2*s - 1
    //   gate B on lane>=32 is o (sigmoid): scale -log2e, v = s
    const float eMul = (l < 32) ? -2.8853900817779268f : -1.4426950408889634f;
    const float vMul = (l < 32) ?  2.0f : 1.0f;
    const float vAdd = (l < 32) ? -1.0f : 0.0f;

    const float wOut = (l < 32) ? w_out[lo] : 0.0f;  // 0 on upper lanes -> clean reduction
    const float bOut = b_out[0];

    // init: h0 = c0 = h1 = c1 = z, pred = 0
    float zv = z[(size_t)b * 32 + lo];
    ((float*)sh0)[l] = zv;        // upper lanes land in padding
    ((float*)sh1)[l] = zv;
    float cc0 = zv, cc1 = zv;
    float pred = 0.0f, sse = 0.0f, xreg = 0.0f, xpred = 0.0f;

    const float* seq_b = seq + (size_t)b * NT;
    float* out_b = out + 1 + (size_t)b * NT;

    __builtin_amdgcn_wave_barrier();   // single wave: DS ops execute in order; fence compiler only

    for (int t = 0; t < NT; ++t) {
        // one coalesced 256B load per 64 steps; lane (t&63) owns step t's residual
        if ((t & 63) == 0) xreg = seq_b[t + l];

        // ---------------- cell 0: gates = pred*w_ih0 + h0 @ w_hh0^T + b0
        float a0 = fmaf(pred, wih0A, bias0A);
        float b0 = fmaf(pred, wih0B, bias0B);
        float a1 = 0.0f, b1 = 0.0f;
        float4 h;
        h = sh0[0]; MAC4(a0, b0, w0A0, w0B0, h);
        h = sh0[1]; MAC4(a1, b1, w0A1, w0B1, h);
        h = sh0[2]; MAC4(a0, b0, w0A2, w0B2, h);
        h = sh0[3]; MAC4(a1, b1, w0A3, w0B3, h);
        h = sh0[4]; MAC4(a0, b0, w0A4, w0B4, h);
        h = sh0[5]; MAC4(a1, b1, w0A5, w0B5, h);
        h = sh0[6]; MAC4(a0, b0, w0A6, w0B6, h);
        h = sh0[7]; MAC4(a1, b1, w0A7, w0B7, h);
        float gA = a0 + a1;   // lane<32: i ; lane>=32: f
        float gB = b0 + b1;   // lane<32: g ; lane>=32: o

        float sA = sig_fast(gA);
        float sB = __builtin_amdgcn_rcpf(1.0f + exp2f(eMul * gB));
        float vB = fmaf(vMul, sB, vAdd);         // tanh(g) on lo / sig(o) on hi

        float fOrI = __shfl_xor(sA, 32);   // lane<32 receives sig(f)
        float oOrG = __shfl_xor(vB, 32);   // lane<32 receives sig(o)
        cc0 = fmaf(fOrI, cc0, sA * vB);          // lanes<32 valid
        float h0n = oOrG * tanh_fast(cc0);
        ((float*)sh0)[l] = h0n;                  // upper-lane garbage -> padding (finite)
        __builtin_amdgcn_wave_barrier();

        // ---------------- cell 1: gates = h0n @ w_ih1^T + h1 @ w_hh1^T + b1
        float cA0 = bias1A, cB0 = bias1B;
        float cA1 = 0.0f,  cB1 = 0.0f;
        float4 u;
        u = sh0[0]; MAC4(cA0, cB0, wiA0, wiB0, u);
        u = sh1[0]; MAC4(cA1, cB1, whA0, whB0, u);
        u = sh0[1]; MAC4(cA0, cB0, wiA1, wiB1, u);
        u = sh1[1]; MAC4(cA1, cB1, whA1, whB1, u);
        u = sh0[2]; MAC4(cA0, cB0, wiA2, wiB2, u);
        u = sh1[2]; MAC4(cA1, cB1, whA2, whB2, u);
        u = sh0[3]; MAC4(cA0, cB0, wiA3, wiB3, u);
        u = sh1[3]; MAC4(cA1, cB1, whA3, whB3, u);
        u = sh0[4]; MAC4(cA0, cB0, wiA4, wiB4, u);
        u = sh1[4]; MAC4(cA1, cB1, whA4, whB4, u);
        u = sh0[5]; MAC4(cA0, cB0, wiA5, wiB5, u);
        u = sh1[5]; MAC4(cA1, cB1, whA5, whB5, u);
        u = sh0[6]; MAC4(cA0, cB0, wiA6, wiB6, u);
        u = sh1[6]; MAC4(cA1, cB1, whA6, whB6, u);
        u = sh0[7]; MAC4(cA0, cB0, wiA7, wiB7, u);
        u = sh1[7]; MAC4(cA1, cB1, whA7, whB7, u);
        float g1A = cA0 + cA1;
        float g1B = cB0 + cB1;

        float s1A = sig_fast(g1A);
        float s1B = __builtin_amdgcn_rcpf(1.0f + exp2f(eMul * g1B));
        float v1B = fmaf(vMul, s1B, vAdd);

        float f1 = __shfl_xor(s1A, 32);
        float o1 = __shfl_xor(v1B, 32);
        cc1 = fmaf(f1, cc1, s1A * v1B);
        float h1n = o1 * tanh_fast(cc1);          // lanes<32 valid, upper finite garbage
        ((float*)sh1)[l] = h1n;

        // pred = b_out + sum_j w_out[j]*h1n[j]  (upper lanes contribute 0 via wOut=0)
        float term = wOut * h1n;
        term += __shfl_xor(term, 1);
        term += __shfl_xor(term, 2);
        term += __shfl_xor(term, 4);
        term += __shfl_xor(term, 8);
        term += __shfl_xor(term, 16);
        term += __shfl_xor(term, 32);
        pred = term + bOut;
        __builtin_amdgcn_wave_barrier();

        // lane (t&63) captures this step's pred; write back coalesced per 64 steps
        xpred = ((t & 63) == l) ? pred : xpred;
        if ((t & 63) == 63) {
            out_b[t - 63 + l] = xpred;           // coalesced 256B store
            float d = xreg - xpred;
            sse = fmaf(d, d, sse);               // each lane owns one step's residual
        }
    }

    // wave-wide SSE reduction, one atomic per block
    sse += __shfl_xor(sse, 1);
    sse += __shfl_xor(sse, 2);
    sse += __shfl_xor(sse, 4);
    sse += __shfl_xor(sse, 8);
    sse += __shfl_xor(sse, 16);
    sse += __shfl_xor(sse, 32);
    if (l == 0) {
        atomicAdd(out, sse * (1.0f / ((float)NB * (float)NT)));  // 1/(B*T) = 2^-21 exact
    }
}

extern "C" void kernel_launch(void* const* d_in, const int* in_sizes, int n_in,
                              void* d_out, int out_size, void* d_ws, size_t ws_size,
                              hipStream_t stream) {
    const float* seq   = (const float*)d_in[0];
    const float* z     = (const float*)d_in[1];
    // d_in[2] = lengths (unused; reference ignores it)
    const float* w_ih0 = (const float*)d_in[3];
    const float* w_hh0 = (const float*)d_in[4];
    const float* b_ih0 = (const float*)d_in[5];
    const float* b_hh0 = (const float*)d_in[6];
    const float* w_ih1 = (const float*)d_in[7];
    const float* w_hh1 = (const float*)d_in[8];
    const float* b_ih1 = (const float*)d_in[9];
    const float* b_hh1 = (const float*)d_in[10];
    const float* w_out = (const float*)d_in[11];
    const float* b_out = (const float*)d_in[12];
    float* out = (float*)d_out;

    hipLaunchKernelGGL(zero_loss_kernel, dim3(1), dim3(1), 0, stream, out);
    hipLaunchKernelGGL(decoder_lstm_kernel, dim3(NB), dim3(64), 0, stream,
                       seq, z, w_ih0, w_hh0, b_ih0, b_hh0,
                       w_ih1, w_hh1, b_ih1, b_hh1, w_out, b_out, out);
}

// Round 4
// 983.876 us; speedup vs baseline: 1.3375x; 1.3375x over previous
//
#include <hip/hip_runtime.h>

#define NB 2048
#define NT 1024

#if __has_builtin(__builtin_amdgcn_fdot2)
#define HAVE_FDOT2 1
#else
#define HAVE_FDOT2 0
#endif

typedef _Float16 half2_t __attribute__((ext_vector_type(2)));
union F4H { float4 f; half2_t h[4]; };

// sigmoid via native exp2 + rcp (v_exp_f32, v_rcp_f32)
__device__ __forceinline__ float sig_fast(float x) {
    return __builtin_amdgcn_rcpf(1.0f + exp2f(-1.4426950408889634f * x));
}
// tanh(x) = 2*sigmoid(2x) - 1
__device__ __forceinline__ float tanh_fast(float x) {
    return fmaf(2.0f, __builtin_amdgcn_rcpf(1.0f + exp2f(-2.8853900817779268f * x)), -1.0f);
}

__global__ void zero_loss_kernel(float* out) { out[0] = 0.0f; }

#define LD4(P, i) (*(const float4*)&(P)[i])

#if HAVE_FDOT2
// ---------------- f16 dot2 path: 96 weight VGPRs, 96 v_dot2 per step ----------------
#define FDOT(acc, w, hh) acc = __builtin_amdgcn_fdot2((w), (hh), (acc), false)
#define PINH(v) asm("" : "+v"(v))

// one f32 float4 -> two packed half2
#define CVTQ(n0, n1, p, i) { float4 r_ = LD4(p, i); \
  n0.x=(_Float16)r_.x; n0.y=(_Float16)r_.y; n1.x=(_Float16)r_.z; n1.y=(_Float16)r_.w; }

// one 32-wide weight row as 16 named half2 (16 VGPRs), pinned against remat
#define DECL_ROWH(n, src, row) \
  half2_t n##0,n##1,n##2,n##3,n##4,n##5,n##6,n##7,n##8,n##9,n##10,n##11,n##12,n##13,n##14,n##15; \
  CVTQ(n##0, n##1, src,(row)*32+ 0) CVTQ(n##2, n##3, src,(row)*32+ 4) \
  CVTQ(n##4, n##5, src,(row)*32+ 8) CVTQ(n##6, n##7, src,(row)*32+12) \
  CVTQ(n##8, n##9, src,(row)*32+16) CVTQ(n##10,n##11,src,(row)*32+20) \
  CVTQ(n##12,n##13,src,(row)*32+24) CVTQ(n##14,n##15,src,(row)*32+28) \
  PINH(n##0); PINH(n##1); PINH(n##2); PINH(n##3); PINH(n##4); PINH(n##5); PINH(n##6); PINH(n##7); \
  PINH(n##8); PINH(n##9); PINH(n##10); PINH(n##11); PINH(n##12); PINH(n##13); PINH(n##14); PINH(n##15);

// 8 dot2 (16 MACs) into two accumulators from one 16B LDS read (4 half2)
#define DOT4(aa, ab, wA0,wA1,wA2,wA3, wB0,wB1,wB2,wB3, U) \
  FDOT(aa, wA0, (U).h[0]); FDOT(ab, wB0, (U).h[0]); \
  FDOT(aa, wA1, (U).h[1]); FDOT(ab, wB1, (U).h[1]); \
  FDOT(aa, wA2, (U).h[2]); FDOT(ab, wB2, (U).h[2]); \
  FDOT(aa, wA3, (U).h[3]); FDOT(ab, wB3, (U).h[3]);
#else
// ---------------- f32 fallback (R3-equivalent) ----------------
struct F4 { float x, y, z, w; };
#define LOADQ(dst, p, i) { float4 r_ = LD4(p, i); dst.x=r_.x; dst.y=r_.y; dst.z=r_.z; dst.w=r_.w; }
#define PIN(v) asm("" : "+v"((v).x), "+v"((v).y), "+v"((v).z), "+v"((v).w))
#define DECL_ROW(n, src, row)                                 \
  F4 n##0, n##1, n##2, n##3, n##4, n##5, n##6, n##7;          \
  LOADQ(n##0, src, (row)*32 +  0) LOADQ(n##1, src, (row)*32 +  4) \
  LOADQ(n##2, src, (row)*32 +  8) LOADQ(n##3, src, (row)*32 + 12) \
  LOADQ(n##4, src, (row)*32 + 16) LOADQ(n##5, src, (row)*32 + 20) \
  LOADQ(n##6, src, (row)*32 + 24) LOADQ(n##7, src, (row)*32 + 28) \
  PIN(n##0); PIN(n##1); PIN(n##2); PIN(n##3); PIN(n##4); PIN(n##5); PIN(n##6); PIN(n##7);
#define MAC4(aa, ab, wA, wB, h)                                \
  aa = fmaf((wA).x, (h).x, aa); ab = fmaf((wB).x, (h).x, ab);  \
  aa = fmaf((wA).y, (h).y, aa); ab = fmaf((wB).y, (h).y, ab);  \
  aa = fmaf((wA).z, (h).z, aa); ab = fmaf((wB).z, (h).z, ab);  \
  aa = fmaf((wA).w, (h).w, aa); ab = fmaf((wB).w, (h).w, ab);
#endif

// Grid = 2048 waves over 1024 SIMDs -> at most 2 waves/SIMD resident anyway;
// cap the allocator's occupancy target there so it has a 256-VGPR budget.
__global__ __launch_bounds__(64) __attribute__((amdgpu_waves_per_eu(2, 2)))
void decoder_lstm_kernel(const float* __restrict__ seq,    // (B,T,1)
                         const float* __restrict__ z,      // (B,32)
                         const float* __restrict__ w_ih0,  // (128,1)
                         const float* __restrict__ w_hh0,  // (128,32)
                         const float* __restrict__ b_ih0,  // (128,)
                         const float* __restrict__ b_hh0,  // (128,)
                         const float* __restrict__ w_ih1,  // (128,32)
                         const float* __restrict__ w_hh1,  // (128,32)
                         const float* __restrict__ b_ih1,  // (128,)
                         const float* __restrict__ b_hh1,  // (128,)
                         const float* __restrict__ w_out,  // (1,32)
                         const float* __restrict__ b_out,  // (1,)
                         float* __restrict__ out)          // [0]=loss, [1..]=recovered (B,T,1)
{
    const int b  = blockIdx.x;     // one wave per batch element
    const int l  = threadIdx.x;    // 0..63
    const int lo = l & 31;

    // lane<32 : rA=i-row, rB=g-row ; lane>=32: rA=f-row, rB=o-row
    const int rA = l;
    const int rB = l + 64;

    const float wih0A  = w_ih0[rA];
    const float wih0B  = w_ih0[rB];
    const float bias0A = b_ih0[rA] + b_hh0[rA];
    const float bias0B = b_ih0[rB] + b_hh0[rB];
    const float bias1A = b_ih1[rA] + b_hh1[rA];
    const float bias1B = b_ih1[rB] + b_hh1[rB];

    // Branchless activation constants:
    //   gate B on lane<32 is g (tanh): exp scale -2*log2e, v = 2s-1
    //   gate B on lane>=32 is o (sigmoid): scale -log2e, v = s
    const float eMul = (l < 32) ? -2.8853900817779268f : -1.4426950408889634f;
    const float vMul = (l < 32) ?  2.0f : 1.0f;
    const float vAdd = (l < 32) ? -1.0f : 0.0f;

    const float wOut = (l < 32) ? w_out[lo] : 0.0f;  // 0 on upper lanes -> clean reduction
    const float bOut = b_out[0];

    float zv = z[(size_t)b * 32 + lo];
    float cc0 = zv, cc1 = zv;
    float pred = 0.0f, sse = 0.0f, xreg = 0.0f, xpred = 0.0f;

    const float* seq_b = seq + (size_t)b * NT;
    float* out_b = out + 1 + (size_t)b * NT;

#if HAVE_FDOT2
    // h vectors live in LDS as f16: 32 live halves + 32 pad halves (lanes>=32
    // store garbage there unconditionally -> no exec-mask fiddling)
    __shared__ float4 sh0f[8];
    __shared__ float4 sh1f[8];
    _Float16* sh0h = (_Float16*)sh0f;
    _Float16* sh1h = (_Float16*)sh1f;

    DECL_ROWH(w0A, w_hh0, rA)
    DECL_ROWH(w0B, w_hh0, rB)
    DECL_ROWH(wiA, w_ih1, rA)
    DECL_ROWH(wiB, w_ih1, rB)
    DECL_ROWH(whA, w_hh1, rA)
    DECL_ROWH(whB, w_hh1, rB)

    sh0h[l] = (_Float16)zv;
    sh1h[l] = (_Float16)zv;
    __builtin_amdgcn_wave_barrier();   // single wave: DS in-order; compiler fence only

    for (int t = 0; t < NT; ++t) {
        if ((t & 63) == 0) xreg = seq_b[t + l];   // coalesced 256B load per 64 steps

        // -------- cell 0: gates = pred*w_ih0 + h0 @ w_hh0^T + b0
        F4H U0, U1, U2, U3;
        U0.f = sh0f[0]; U1.f = sh0f[1]; U2.f = sh0f[2]; U3.f = sh0f[3];
        float a0 = fmaf(pred, wih0A, bias0A), a1 = 0.0f;
        float b0 = fmaf(pred, wih0B, bias0B), b1 = 0.0f;
        DOT4(a0, b0, w0A0,w0A1,w0A2,w0A3,     w0B0,w0B1,w0B2,w0B3,     U0);
        DOT4(a1, b1, w0A4,w0A5,w0A6,w0A7,     w0B4,w0B5,w0B6,w0B7,     U1);
        DOT4(a0, b0, w0A8,w0A9,w0A10,w0A11,   w0B8,w0B9,w0B10,w0B11,   U2);
        DOT4(a1, b1, w0A12,w0A13,w0A14,w0A15, w0B12,w0B13,w0B14,w0B15, U3);
        float gA = a0 + a1;   // lane<32: i ; lane>=32: f
        float gB = b0 + b1;   // lane<32: g ; lane>=32: o

        float sA = sig_fast(gA);
        float sB = __builtin_amdgcn_rcpf(1.0f + exp2f(eMul * gB));
        float vB = fmaf(vMul, sB, vAdd);         // tanh(g) on lo / sig(o) on hi

        float fOrI = __shfl_xor(sA, 32);
        float oOrG = __shfl_xor(vB, 32);
        cc0 = fmaf(fOrI, cc0, sA * vB);          // lanes<32 valid
        float h0n = oOrG * tanh_fast(cc0);
        sh0h[l] = (_Float16)h0n;                 // upper-lane garbage -> pad (finite)
        __builtin_amdgcn_wave_barrier();

        // -------- cell 1: gates = h0n @ w_ih1^T + h1 @ w_hh1^T + b1
        F4H V0, V1, V2, V3, X0, X1, X2, X3;
        V0.f = sh0f[0]; V1.f = sh0f[1]; V2.f = sh0f[2]; V3.f = sh0f[3];
        X0.f = sh1f[0]; X1.f = sh1f[1]; X2.f = sh1f[2]; X3.f = sh1f[3];
        float cA0 = bias1A, cA1 = 0.0f;
        float cB0 = bias1B, cB1 = 0.0f;
        DOT4(cA0, cB0, wiA0,wiA1,wiA2,wiA3,     wiB0,wiB1,wiB2,wiB3,     V0);
        DOT4(cA1, cB1, wiA4,wiA5,wiA6,wiA7,     wiB4,wiB5,wiB6,wiB7,     V1);
        DOT4(cA0, cB0, wiA8,wiA9,wiA10,wiA11,   wiB8,wiB9,wiB10,wiB11,   V2);
        DOT4(cA1, cB1, wiA12,wiA13,wiA14,wiA15, wiB12,wiB13,wiB14,wiB15, V3);
        DOT4(cA0, cB0, whA0,whA1,whA2,whA3,     whB0,whB1,whB2,whB3,     X0);
        DOT4(cA1, cB1, whA4,whA5,whA6,whA7,     whB4,whB5,whB6,whB7,     X1);
        DOT4(cA0, cB0, whA8,whA9,whA10,whA11,   whB8,whB9,whB10,whB11,   X2);
        DOT4(cA1, cB1, whA12,whA13,whA14,whA15, whB12,whB13,whB14,whB15, X3);
        float g1A = cA0 + cA1;
        float g1B = cB0 + cB1;

        float s1A = sig_fast(g1A);
        float s1B = __builtin_amdgcn_rcpf(1.0f + exp2f(eMul * g1B));
        float v1B = fmaf(vMul, s1B, vAdd);

        float f1 = __shfl_xor(s1A, 32);
        float o1 = __shfl_xor(v1B, 32);
        cc1 = fmaf(f1, cc1, s1A * v1B);
        float h1n = o1 * tanh_fast(cc1);          // lanes<32 valid
        sh1h[l] = (_Float16)h1n;

        // pred = b_out + sum_j w_out[j]*h1n[j] (upper lanes contribute 0)
        float term = wOut * h1n;
        term += __shfl_xor(term, 1);
        term += __shfl_xor(term, 2);
        term += __shfl_xor(term, 4);
        term += __shfl_xor(term, 8);
        term += __shfl_xor(term, 16);
        term += __shfl_xor(term, 32);
        pred = term + bOut;
        __builtin_amdgcn_wave_barrier();

        // lane (t&63) captures this step's pred; coalesced write each 64 steps
        xpred = ((t & 63) == l) ? pred : xpred;
        if ((t & 63) == 63) {
            out_b[t - 63 + l] = xpred;
            float d = xreg - xpred;
            sse = fmaf(d, d, sse);
        }
    }
#else
    __shared__ float4 sh0[16];
    __shared__ float4 sh1[16];

    DECL_ROW(w0A, w_hh0, rA)
    DECL_ROW(w0B, w_hh0, rB)
    DECL_ROW(wiA, w_ih1, rA)
    DECL_ROW(wiB, w_ih1, rB)
    DECL_ROW(whA, w_hh1, rA)
    DECL_ROW(whB, w_hh1, rB)

    ((float*)sh0)[l] = zv;
    ((float*)sh1)[l] = zv;
    __builtin_amdgcn_wave_barrier();

    for (int t = 0; t < NT; ++t) {
        if ((t & 63) == 0) xreg = seq_b[t + l];

        float a0 = fmaf(pred, wih0A, bias0A);
        float b0 = fmaf(pred, wih0B, bias0B);
        float a1 = 0.0f, b1 = 0.0f;
        float4 h;
        h = sh0[0]; MAC4(a0, b0, w0A0, w0B0, h);
        h = sh0[1]; MAC4(a1, b1, w0A1, w0B1, h);
        h = sh0[2]; MAC4(a0, b0, w0A2, w0B2, h);
        h = sh0[3]; MAC4(a1, b1, w0A3, w0B3, h);
        h = sh0[4]; MAC4(a0, b0, w0A4, w0B4, h);
        h = sh0[5]; MAC4(a1, b1, w0A5, w0B5, h);
        h = sh0[6]; MAC4(a0, b0, w0A6, w0B6, h);
        h = sh0[7]; MAC4(a1, b1, w0A7, w0B7, h);
        float gA = a0 + a1;
        float gB = b0 + b1;

        float sA = sig_fast(gA);
        float sB = __builtin_amdgcn_rcpf(1.0f + exp2f(eMul * gB));
        float vB = fmaf(vMul, sB, vAdd);

        float fOrI = __shfl_xor(sA, 32);
        float oOrG = __shfl_xor(vB, 32);
        cc0 = fmaf(fOrI, cc0, sA * vB);
        float h0n = oOrG * tanh_fast(cc0);
        ((float*)sh0)[l] = h0n;
        __builtin_amdgcn_wave_barrier();

        float cA0 = bias1A, cB0 = bias1B;
        float cA1 = 0.0f,  cB1 = 0.0f;
        float4 u;
        u = sh0[0]; MAC4(cA0, cB0, wiA0, wiB0, u);
        u = sh1[0]; MAC4(cA1, cB1, whA0, whB0, u);
        u = sh0[1]; MAC4(cA0, cB0, wiA1, wiB1, u);
        u = sh1[1]; MAC4(cA1, cB1, whA1, whB1, u);
        u = sh0[2]; MAC4(cA0, cB0, wiA2, wiB2, u);
        u = sh1[2]; MAC4(cA1, cB1, whA2, whB2, u);
        u = sh0[3]; MAC4(cA0, cB0, wiA3, wiB3, u);
        u = sh1[3]; MAC4(cA1, cB1, whA3, whB3, u);
        u = sh0[4]; MAC4(cA0, cB0, wiA4, wiB4, u);
        u = sh1[4]; MAC4(cA1, cB1, whA4, whB4, u);
        u = sh0[5]; MAC4(cA0, cB0, wiA5, wiB5, u);
        u = sh1[5]; MAC4(cA1, cB1, whA5, whB5, u);
        u = sh0[6]; MAC4(cA0, cB0, wiA6, wiB6, u);
        u = sh1[6]; MAC4(cA1, cB1, whA6, whB6, u);
        u = sh0[7]; MAC4(cA0, cB0, wiA7, wiB7, u);
        u = sh1[7]; MAC4(cA1, cB1, whA7, whB7, u);
        float g1A = cA0 + cA1;
        float g1B = cB0 + cB1;

        float s1A = sig_fast(g1A);
        float s1B = __builtin_amdgcn_rcpf(1.0f + exp2f(eMul * g1B));
        float v1B = fmaf(vMul, s1B, vAdd);

        float f1 = __shfl_xor(s1A, 32);
        float o1 = __shfl_xor(v1B, 32);
        cc1 = fmaf(f1, cc1, s1A * v1B);
        float h1n = o1 * tanh_fast(cc1);
        ((float*)sh1)[l] = h1n;

        float term = wOut * h1n;
        term += __shfl_xor(term, 1);
        term += __shfl_xor(term, 2);
        term += __shfl_xor(term, 4);
        term += __shfl_xor(term, 8);
        term += __shfl_xor(term, 16);
        term += __shfl_xor(term, 32);
        pred = term + bOut;
        __builtin_amdgcn_wave_barrier();

        xpred = ((t & 63) == l) ? pred : xpred;
        if ((t & 63) == 63) {
            out_b[t - 63 + l] = xpred;
            float d = xreg - xpred;
            sse = fmaf(d, d, sse);
        }
    }
#endif

    // wave-wide SSE reduction, one atomic per block
    sse += __shfl_xor(sse, 1);
    sse += __shfl_xor(sse, 2);
    sse += __shfl_xor(sse, 4);
    sse += __shfl_xor(sse, 8);
    sse += __shfl_xor(sse, 16);
    sse += __shfl_xor(sse, 32);
    if (l == 0) {
        atomicAdd(out, sse * (1.0f / ((float)NB * (float)NT)));  // 1/(B*T) = 2^-21 exact
    }
}

extern "C" void kernel_launch(void* const* d_in, const int* in_sizes, int n_in,
                              void* d_out, int out_size, void* d_ws, size_t ws_size,
                              hipStream_t stream) {
    const float* seq   = (const float*)d_in[0];
    const float* z     = (const float*)d_in[1];
    // d_in[2] = lengths (unused; reference ignores it)
    const float* w_ih0 = (const float*)d_in[3];
    const float* w_hh0 = (const float*)d_in[4];
    const float* b_ih0 = (const float*)d_in[5];
    const float* b_hh0 = (const float*)d_in[6];
    const float* w_ih1 = (const float*)d_in[7];
    const float* w_hh1 = (const float*)d_in[8];
    const float* b_ih1 = (const float*)d_in[9];
    const float* b_hh1 = (const float*)d_in[10];
    const float* w_out = (const float*)d_in[11];
    const float* b_out = (const float*)d_in[12];
    float* out = (float*)d_out;

    hipLaunchKernelGGL(zero_loss_kernel, dim3(1), dim3(1), 0, stream, out);
    hipLaunchKernelGGL(decoder_lstm_kernel, dim3(NB), dim3(64), 0, stream,
                       seq, z, w_ih0, w_hh0, b_ih0, b_hh0,
                       w_ih1, w_hh1, b_ih1, b_hh1, w_out, b_out, out);
}

// Round 6
// 927.735 us; speedup vs baseline: 1.4185x; 1.0605x over previous
//
#include <hip/hip_runtime.h>

#define NB 2048
#define NT 1024

typedef _Float16 f16x8 __attribute__((ext_vector_type(8)));
typedef _Float16 f16x2 __attribute__((ext_vector_type(2)));
typedef float    f32x4 __attribute__((ext_vector_type(4)));

#define MFMA16(a, b, c) __builtin_amdgcn_mfma_f32_16x16x32_f16((a), (b), (c), 0, 0, 0)

// sigmoid / tanh via native exp2 + rcp
__device__ __forceinline__ float sig_fast(float x) {
    return __builtin_amdgcn_rcpf(1.0f + __builtin_amdgcn_exp2f(-1.4426950408889634f * x));
}
__device__ __forceinline__ float tanh_fast(float x) {
    return fmaf(2.0f, __builtin_amdgcn_rcpf(1.0f + __builtin_amdgcn_exp2f(-2.8853900817779268f * x)), -1.0f);
}

__global__ void zero_loss_kernel(float* out) { out[0] = 0.0f; }

// 8 consecutive f32 -> f16x8 MFMA fragment (k-slots in memory order; the same
// k-slot ordering is used for the LDS h-tiles, so the contraction is correct
// for any internal k permutation of the symmetric f16 MFMA A/B layouts)
__device__ __forceinline__ f16x8 load_frag8(const float* __restrict__ p) {
    float4 a = *(const float4*)p;
    float4 b = *(const float4*)(p + 4);
    f16x8 r;
    r[0] = (_Float16)a.x; r[1] = (_Float16)a.y; r[2] = (_Float16)a.z; r[3] = (_Float16)a.w;
    r[4] = (_Float16)b.x; r[5] = (_Float16)b.y; r[6] = (_Float16)b.z; r[7] = (_Float16)b.w;
    return r;
}

__device__ __forceinline__ f16x2 pack2(float a, float b) {
    f16x2 r;
    r[0] = (_Float16)a;
    r[1] = (_Float16)b;
    return r;
}

// Block = 16 batch columns, 2 waves (wave w owns hidden rows [16w,16w+16) of
// every gate). Weights = loop-invariant MFMA A-fragments (48 VGPRs/lane).
// h0/h1 live in LDS as f16 [n][k] tiles (padded to 40 halves/row: 80B stride
// -> worst aliasing 2-way = free), ping-ponged by step parity.
#define HROW 40

__global__ __launch_bounds__(128) __attribute__((amdgpu_waves_per_eu(1)))
void decoder_lstm_kernel(const float* __restrict__ seq,    // (B,T,1)
                         const float* __restrict__ z,      // (B,32)
                         const float* __restrict__ w_ih0,  // (128,1)
                         const float* __restrict__ w_hh0,  // (128,32)
                         const float* __restrict__ b_ih0,  // (128,)
                         const float* __restrict__ b_hh0,  // (128,)
                         const float* __restrict__ w_ih1,  // (128,32)
                         const float* __restrict__ w_hh1,  // (128,32)
                         const float* __restrict__ b_ih1,  // (128,)
                         const float* __restrict__ b_hh1,  // (128,)
                         const float* __restrict__ w_out,  // (1,32)
                         const float* __restrict__ b_out,  // (1,)
                         float* __restrict__ out)          // [0]=loss, [1..]=recovered (B,T,1)
{
    const int tid = threadIdx.x;
    const int w   = tid >> 6;        // wave id: hidden half
    const int l   = tid & 63;        // lane
    const int n   = l & 15;          // batch col of this lane (B-frag col / C-frag col)
    const int g   = l >> 4;          // k-group (A/B frags) and row-group (C frags)
    const int blk = blockIdx.x;
    const int bg  = blk * 16 + n;    // global batch index of this lane's column

    __shared__ __align__(16) _Float16 hbuf[2][2][16 * HROW];  // [h0/h1][parity][n*HROW+k]
    __shared__ float pb[2][16];                                // pred partials per wave

    // ---- loop-invariant A-fragments: A row m = l&15, k = 8g..8g+7
    f16x8 a0f[4], a1if[4], a1hf[4];
#pragma unroll
    for (int G = 0; G < 4; ++G) {
        const int R = G * 32 + 16 * w + (l & 15);   // global gate row
        a0f[G]  = load_frag8(&w_hh0[R * 32 + 8 * g]);
        a1if[G] = load_frag8(&w_ih1[R * 32 + 8 * g]);
        a1hf[G] = load_frag8(&w_hh1[R * 32 + 8 * g]);
    }

    // ---- per-lane consts for C-fragment rows r = G*32 + 16w + 4g + q
    f32x4 bias0v[4], bias1v[4], wih0v[4];
#pragma unroll
    for (int G = 0; G < 4; ++G) {
#pragma unroll
        for (int q = 0; q < 4; ++q) {
            const int r = G * 32 + 16 * w + 4 * g + q;
            bias0v[G][q] = b_ih0[r] + b_hh0[r];
            bias1v[G][q] = b_ih1[r] + b_hh1[r];
            wih0v[G][q]  = w_ih0[r];
        }
    }
    float woutc[4];
#pragma unroll
    for (int q = 0; q < 4; ++q) woutc[q] = w_out[16 * w + 4 * g + q];
    const float bOut = b_out[0];

    // ---- state init: h0=c0=h1=c1=z, pred=0
    // c fragments: rows 16w+4g+q, col n -> 4 consecutive z values
    f32x4 c0, c1;
    {
        float4 cz = *(const float4*)&z[(size_t)bg * 32 + 16 * w + 4 * g];
        c0[0] = cz.x; c0[1] = cz.y; c0[2] = cz.z; c0[3] = cz.w;
        c1 = c0;
    }
    // h buffers (parity 1 is read at step 0): wave w fills hbuf[w][1]
    {
        f16x8 hz = load_frag8(&z[(size_t)bg * 32 + 8 * g]);
        *(f16x8*)&hbuf[w][1][n * HROW + 8 * g] = hz;
    }
    __syncthreads();

    float pred = 0.0f, sse = 0.0f;
    float xp0 = 0.f, xp1 = 0.f, xp2 = 0.f, xp3 = 0.f;   // wave0 pred capture (phase = g)

    for (int tb = 0; tb < NT; tb += 4) {
        const bool cap = (w == 0) && (((tb >> 2) & 3) == g);
#pragma unroll
        for (int j = 0; j < 4; ++j) {
            const int par = j & 1;   // step parity (tb multiple of 4)

            // ======== cell 0: gates0 = Whh0 @ h0 + (b0 + pred*wih0) ========
            f16x8 hb0 = *(const f16x8*)&hbuf[0][par ^ 1][n * HROW + 8 * g];
            f32x4 acc0[4];
#pragma unroll
            for (int G = 0; G < 4; ++G) {
                f32x4 ci;
#pragma unroll
                for (int q = 0; q < 4; ++q) ci[q] = fmaf(pred, wih0v[G][q], bias0v[G][q]);
                acc0[G] = MFMA16(a0f[G], hb0, ci);
            }
            // activations: per lane 4 hidden rows, gates i/f/g/o aligned per row
            f32x4 h0n;
#pragma unroll
            for (int q = 0; q < 4; ++q) {
                float si = sig_fast(acc0[0][q]);
                float sf = sig_fast(acc0[1][q]);
                float tg = tanh_fast(acc0[2][q]);
                float so = sig_fast(acc0[3][q]);
                float c  = fmaf(sf, c0[q], si * tg);
                c0[q]    = c;
                h0n[q]   = so * tanh_fast(c);
            }
            // scatter h0n -> hbuf[0][par] at [n][16w+4g+{0..3}]
            {
                const int kk = 16 * w + 4 * g;
                *(f16x2*)&hbuf[0][par][n * HROW + kk]     = pack2(h0n[0], h0n[1]);
                *(f16x2*)&hbuf[0][par][n * HROW + kk + 2] = pack2(h0n[2], h0n[3]);
            }
            __syncthreads();   // h0n exchange

            // ======== cell 1: gates1 = Wih1 @ h0n + Whh1 @ h1 + b1 ========
            f16x8 hb0n = *(const f16x8*)&hbuf[0][par][n * HROW + 8 * g];
            f16x8 hb1  = *(const f16x8*)&hbuf[1][par ^ 1][n * HROW + 8 * g];
            f32x4 acc1[4];
#pragma unroll
            for (int G = 0; G < 4; ++G) {
                f32x4 t   = MFMA16(a1if[G], hb0n, bias1v[G]);
                acc1[G]   = MFMA16(a1hf[G], hb1, t);
            }
            f32x4 h1n;
#pragma unroll
            for (int q = 0; q < 4; ++q) {
                float si = sig_fast(acc1[0][q]);
                float sf = sig_fast(acc1[1][q]);
                float tg = tanh_fast(acc1[2][q]);
                float so = sig_fast(acc1[3][q]);
                float c  = fmaf(sf, c1[q], si * tg);
                c1[q]    = c;
                h1n[q]   = so * tanh_fast(c);
            }
            // h1n -> hbuf[1][par]
            {
                const int kk = 16 * w + 4 * g;
                *(f16x2*)&hbuf[1][par][n * HROW + kk]     = pack2(h1n[0], h1n[1]);
                *(f16x2*)&hbuf[1][par][n * HROW + kk + 2] = pack2(h1n[2], h1n[3]);
            }
            // pred partial: this wave's 16 hidden rows of w_out . h1n
            float part = fmaf(h1n[0], woutc[0],
                         fmaf(h1n[1], woutc[1],
                         fmaf(h1n[2], woutc[2], h1n[3] * woutc[3])));
            part += __shfl_xor(part, 16);
            part += __shfl_xor(part, 32);
            if (l < 16) pb[w][l] = part;
            __syncthreads();   // h1n + pred exchange

            pred = bOut + pb[0][n] + pb[1][n];

            // wave0 lane (n, g) captures steps tb..tb+3 when (tb>>2)&3 == g
            if (cap) {
                if (j == 0) xp0 = pred;
                if (j == 1) xp1 = pred;
                if (j == 2) xp2 = pred;
                if (j == 3) xp3 = pred;
            }
        }

        // every 16 steps wave0 dumps 16x16 preds (lane -> (n, 4 steps at 4g))
        if ((tb & 15) == 12 && w == 0) {
            const int t0 = (tb & ~15) + 4 * g;
            const size_t base = (size_t)bg * NT + t0;
            float s0 = seq[base + 0], s1 = seq[base + 1], s2 = seq[base + 2], s3 = seq[base + 3];
            out[1 + base + 0] = xp0;
            out[1 + base + 1] = xp1;
            out[1 + base + 2] = xp2;
            out[1 + base + 3] = xp3;
            float d0 = s0 - xp0, d1 = s1 - xp1, d2 = s2 - xp2, d3 = s3 - xp3;
            sse = fmaf(d0, d0, sse);
            sse = fmaf(d1, d1, sse);
            sse = fmaf(d2, d2, sse);
            sse = fmaf(d3, d3, sse);
        }
    }

    // loss: wave0 reduce + one atomic per block; 1/(B*T) = 2^-21 exact
    if (w == 0) {
        sse += __shfl_xor(sse, 1);
        sse += __shfl_xor(sse, 2);
        sse += __shfl_xor(sse, 4);
        sse += __shfl_xor(sse, 8);
        sse += __shfl_xor(sse, 16);
        sse += __shfl_xor(sse, 32);
        if (l == 0) atomicAdd(out, sse * (1.0f / ((float)NB * (float)NT)));
    }
}

extern "C" void kernel_launch(void* const* d_in, const int* in_sizes, int n_in,
                              void* d_out, int out_size, void* d_ws, size_t ws_size,
                              hipStream_t stream) {
    const float* seq   = (const float*)d_in[0];
    const float* z     = (const float*)d_in[1];
    // d_in[2] = lengths (unused; reference ignores it)
    const float* w_ih0 = (const float*)d_in[3];
    const float* w_hh0 = (const float*)d_in[4];
    const float* b_ih0 = (const float*)d_in[5];
    const float* b_hh0 = (const float*)d_in[6];
    const float* w_ih1 = (const float*)d_in[7];
    const float* w_hh1 = (const float*)d_in[8];
    const float* b_ih1 = (const float*)d_in[9];
    const float* b_hh1 = (const float*)d_in[10];
    const float* w_out = (const float*)d_in[11];
    const float* b_out = (const float*)d_in[12];
    float* out = (float*)d_out;

    hipLaunchKernelGGL(zero_loss_kernel, dim3(1), dim3(1), 0, stream, out);
    hipLaunchKernelGGL(decoder_lstm_kernel, dim3(NB / 16), dim3(128), 0, stream,
                       seq, z, w_ih0, w_hh0, b_ih0, b_hh0,
                       w_ih1, w_hh1, b_ih1, b_hh1, w_out, b_out, out);
}